// Round 4
// 270.570 us; speedup vs baseline: 1.0028x; 1.0028x over previous
//
#include <hip/hip_runtime.h>
#include <hip/hip_bf16.h>

// DPP helper: float lane-crossing via v_mov_b32_dpp (VALU, ~4cyc; no DS).
// bound_ctrl=true -> lanes with invalid source read 0.0f.
#define DPPF(x, ctrl) \
    __int_as_float(__builtin_amdgcn_mov_dpp(__float_as_int(x), (ctrl), 0xf, 0xf, true))

// ---------------------------------------------------------------------------
// Kernel 1: one WAVE per (b,t) row; 64 lanes x 16 floats = 1024 = V.
// Emits gat[row][lane] = float4{ P(lab 2k), P(lab 2k+1), P(blank), 0 } —
// PROBABILITIES (softmax), not log-probs: the alpha recursion runs in the
// linear domain with periodic power-of-2 renorm. Also zeroes out[0].
// ---------------------------------------------------------------------------
__global__ void lse_gather_kernel(const float* __restrict__ pred,
                                  const int* __restrict__ tgt,
                                  float4* __restrict__ gat,
                                  float* __restrict__ out,
                                  int T, int V, int L, int nrows) {
    if (blockIdx.x == 0 && threadIdx.x == 0) out[0] = 0.0f;

    const int wid = blockIdx.x * (blockDim.x >> 6) + (threadIdx.x >> 6);
    if (wid >= nrows) return;
    const int lane = threadIdx.x & 63;
    const int b = wid / T;

    const float* row = pred + (size_t)wid * V;   // wid == b*T + t
    float4 w0 = ((const float4*)row)[lane];
    float4 w1 = ((const float4*)row)[lane + 64];
    float4 w2 = ((const float4*)row)[lane + 128];
    float4 w3 = ((const float4*)row)[lane + 192];

    float m = fmaxf(fmaxf(fmaxf(w0.x, w0.y), fmaxf(w0.z, w0.w)),
                    fmaxf(fmaxf(w1.x, w1.y), fmaxf(w1.z, w1.w)));
    m = fmaxf(m, fmaxf(fmaxf(w2.x, w2.y), fmaxf(w2.z, w2.w)));
    m = fmaxf(m, fmaxf(fmaxf(w3.x, w3.y), fmaxf(w3.z, w3.w)));
    #pragma unroll
    for (int off = 1; off < 64; off <<= 1) m = fmaxf(m, __shfl_xor(m, off, 64));

    float s = __expf(w0.x - m) + __expf(w0.y - m) + __expf(w0.z - m) + __expf(w0.w - m)
            + __expf(w1.x - m) + __expf(w1.y - m) + __expf(w1.z - m) + __expf(w1.w - m)
            + __expf(w2.x - m) + __expf(w2.y - m) + __expf(w2.z - m) + __expf(w2.w - m)
            + __expf(w3.x - m) + __expf(w3.y - m) + __expf(w3.z - m) + __expf(w3.w - m);
    #pragma unroll
    for (int off = 1; off < 64; off <<= 1) s += __shfl_xor(s, off, 64);

    const float lse = m + __logf(s);

    float pz = __expf(row[0] - lse);        // blank probability
    float px = 0.0f, py = 0.0f;             // 0 = additive identity: masks
    const int l0 = 2 * lane, l1i = 2 * lane + 1;
    if (l0  < L) px = __expf(row[tgt[b * L + l0 ]] - lse);  // row is L1-hot
    if (l1i < L) py = __expf(row[tgt[b * L + l1i]] - lse);

    float4 o; o.x = px; o.y = py; o.z = pz; o.w = 0.0f;
    gat[(size_t)wid * 64 + lane] = o;
}

// ---------------------------------------------------------------------------
// Kernel 2: CTC alpha, ONE WAVE per batch element, LINEAR (prob) domain.
// EXACT round-0 verified kernel with ONE change: __launch_bounds__(64, 1).
// Round-0 PMC showed VGPR_Count=44 — the 24-deep P[24] prefetch ring (needs
// >=96 VGPR) was COLLAPSED by the register allocator, leaving ~2-3 effective
// outstanding loads -> ~200 cyc/step exposed latency (83.4 us). With
// (64,1) the allocator gets the full 512-VGPR budget (1 wave/EU floor is
// all this 32-wave grid can use anyway), so the ring can stay resident.
// Diagnostic for next round: VGPR_Count >=150 <=> ring materialized.
// ---------------------------------------------------------------------------
__global__ __launch_bounds__(64, 1)
void ctc_alpha_wave(const float4* __restrict__ gat,
                    const int* __restrict__ tgt,
                    const int* __restrict__ in_len,
                    const int* __restrict__ tg_len,
                    float* __restrict__ out,
                    int T, int L, int B) {
    const int b = blockIdx.x;
    const int k = threadIdx.x;              // single wave, block = 64
    const int S = 2 * L + 1;

    const int il = in_len[b];
    const int tl = tg_len[b];
    const float4* gb = gat + (size_t)b * T * 64;

    const bool v1 = (4 * k + 1 < S);
    const bool v3 = (4 * k + 3 < S);
    bool sk1 = false, sk3 = false;
    if (v1 && k > 0) {
        int tc = tgt[b * L + 2 * k], tp = tgt[b * L + 2 * k - 1];
        sk1 = (tc != 0) && (tc != tp);
    }
    if (v3) {
        int tc = tgt[b * L + 2 * k + 1], tp = tgt[b * L + 2 * k];
        sk3 = (tc != 0) && (tc != tp);
    }

    // t = 0 init (probabilities)
    float q0 = 0.0f, q1 = 0.0f, q2 = 0.0f, q3 = 0.0f;
    {
        float4 f0 = gb[k];
        if (k == 0) { q0 = f0.z; q1 = (tl > 0) ? f0.x : 0.0f; }
    }
    int acc = 0;                            // running log2 scale (integer)

    const int tmax = (il < T) ? il : T;
    const int rmax = T - 1;

    // 24-deep register prefetch ring (Little's law: 24 / ~450cyc L3 latency
    // sustains one row per ~19cyc > consumption rate)
    float4 P[24];
    #pragma unroll
    for (int d = 0; d < 24; ++d) {
        int r = 1 + d; r = (r > rmax) ? rmax : r;
        P[d] = gb[(size_t)r * 64 + k];
    }

    int t = 1;

#define STEP(p)                                                              \
    {                                                                        \
        float qm = DPPF(q3, 0x138);          /* wave_shr:1 -> lane k-1 q3 */ \
        qm = (k == 0) ? 0.0f : qm;                                           \
        float n0 = (q0 + qm) * (p).z;                                        \
        float n1 = (q1 + q0 + (sk1 ? qm : 0.0f)) * (p).x;                    \
        float n2 = (q2 + q1) * (p).z;                                        \
        float n3 = (q3 + q2 + (sk3 ? q1 : 0.0f)) * (p).y;                    \
        q0 = n0; q1 = n1; q2 = n2; q3 = n3;                                  \
        ++t;                                                                 \
    }

// exact power-of-2 renorm: brings wave max's exponent to 0; no rounding.
#define RENORM                                                               \
    {                                                                        \
        float mx = fmaxf(fmaxf(q0, q1), fmaxf(q2, q3));                      \
        mx = fmaxf(mx, DPPF(mx, 0x111));     /* row_shr:1  */                \
        mx = fmaxf(mx, DPPF(mx, 0x112));     /* row_shr:2  */                \
        mx = fmaxf(mx, DPPF(mx, 0x114));     /* row_shr:4  */                \
        mx = fmaxf(mx, DPPF(mx, 0x118));     /* row_shr:8  */                \
        mx = fmaxf(mx, DPPF(mx, 0x142));     /* row_bcast:15 */              \
        mx = fmaxf(mx, DPPF(mx, 0x143));     /* row_bcast:31 */              \
        int me = (__builtin_amdgcn_readlane(__float_as_int(mx), 63) >> 23) & 0xff; \
        float sc = __int_as_float(((me == 0) ? 127 : (254 - me)) << 23);     \
        acc += (me == 0) ? 0 : (me - 127);                                   \
        q0 *= sc; q1 *= sc; q2 *= sc; q3 *= sc;                              \
    }

    while (t + 24 <= tmax) {
        #pragma unroll
        for (int u = 0; u < 24; ++u) {
            float4 p = P[u];
            { int r = t + 24; r = (r > rmax) ? rmax : r;
              P[u] = gb[(size_t)r * 64 + k]; }
            STEP(p)
            if ((u & 3) == 3) RENORM
        }
    }
    while (t + 4 <= tmax) {                  // remainder rows are cache-warm
        { float4 pa = gb[(size_t)t * 64 + k]; STEP(pa) }
        { float4 pb = gb[(size_t)t * 64 + k]; STEP(pb) }
        { float4 pc = gb[(size_t)t * 64 + k]; STEP(pc) }
        { float4 pd = gb[(size_t)t * 64 + k]; STEP(pd) }
        RENORM
    }
    while (t < tmax) {
        float4 pr = gb[(size_t)t * 64 + k]; STEP(pr)
    }
#undef STEP
#undef RENORM

    // final = logaddexp(alpha[2*tl], alpha[2*tl-1]) at t = il-1
    const int e1 = 2 * tl;
    const int e2 = (2 * tl - 1 > 0) ? (2 * tl - 1) : 0;
    const int i1 = e1 & 3, l1 = e1 >> 2;
    const int i2 = e2 & 3, l2 = e2 >> 2;
    float m1 = (i1 == 0) ? q0 : (i1 == 1) ? q1 : (i1 == 2) ? q2 : q3;
    float m2 = (i2 == 0) ? q0 : (i2 == 1) ? q1 : (i2 == 2) ? q2 : q3;
    float ev1 = __shfl(m1, l1, 64);
    float ev2 = __shfl(m2, l2, 64);
    float qs = ev1 + ev2;

    if (k == 0) {
        float loss = 0.0f;
        if (qs > 0.0f && il >= 1 && il <= T) {
            float fin_log2 = (float)acc + log2f(qs);
            loss = -fin_log2 * 0.6931471805599453f;      // ln2
        }
        atomicAdd(out, loss / ((float)tl * (float)B));
    }
}

extern "C" void kernel_launch(void* const* d_in, const int* in_sizes, int n_in,
                              void* d_out, int out_size, void* d_ws, size_t ws_size,
                              hipStream_t stream) {
    const float* pred = (const float*)d_in[0];
    const int*   plen = (const int*)d_in[1];
    const int*   gt   = (const int*)d_in[2];
    const int*   glen = (const int*)d_in[3];
    float* out = (float*)d_out;

    const int B = in_sizes[1];
    const int L = in_sizes[2] / B;
    const int V = 1024;                      // problem-fixed (reference setup)
    const int T = in_sizes[0] / B / V;

    float4* gat = (float4*)d_ws;             // B*T*64 float4 = ~32.8 MiB

    const int nrows = B * T;                 // one wave per row
    const int wavesPerBlk = 4;               // block = 256
    const int nblk = (nrows + wavesPerBlk - 1) / wavesPerBlk;
    lse_gather_kernel<<<nblk, 64 * wavesPerBlk, 0, stream>>>(
        pred, gt, gat, out, T, V, L, nrows);

    ctc_alpha_wave<<<B, 64, 0, stream>>>(gat, gt, plen, glen, out, T, L, B);
}